// Round 16
// baseline (170.511 us; speedup 1.0000x reference)
//
#include <hip/hip_runtime.h>
#include <hip/hip_bf16.h>
#include <cstdint>
#include <cstddef>

typedef short  s16x8 __attribute__((ext_vector_type(8)));
typedef short  s16x4 __attribute__((ext_vector_type(4)));
typedef float  f32x4 __attribute__((ext_vector_type(4)));
typedef unsigned u32x2 __attribute__((ext_vector_type(2)));

static constexpr int Bb = 4, Ss = 2048, Dd = 512, Hh = 8, HDd = 64, FFf = 2048;
static constexpr int Mm = Bb * Ss; // 8192

__device__ __forceinline__ unsigned short f2bf(float f) {
  unsigned u = __float_as_uint(f);
  u += 0x7FFFu + ((u >> 16) & 1u);   // RNE
  return (unsigned short)(u >> 16);
}

__device__ __forceinline__ unsigned cvt_pk_bf16(float lo, float hi) {
  unsigned r;
  asm("v_cvt_pk_bf16_f32 %0, %1, %2" : "=v"(r) : "v"(lo), "v"(hi));
  return r;
}

// raw hardware exp2 (inputs bounded by defer-max; underflow->0 is desired)
__device__ __forceinline__ float exp2_raw(float x) {
  float r;
  asm("v_exp_f32 %0, %1\n\ts_nop 0" : "=v"(r) : "v"(x));
  return r;
}

#define GLOAD_LDS16(gp, lp)                                                     \
  __builtin_amdgcn_global_load_lds((const __attribute__((address_space(1))) void*)(gp), \
                                   (__attribute__((address_space(3))) void*)(lp), 16, 0, 0)

// ---------- fused prep: emb cvt + QKV weight prep + 3 transposes + mask ----------
__device__ __forceinline__ void xpose_tile(const float* __restrict__ in,
                                           unsigned short* __restrict__ out,
                                           int K, int N, int bx, int by, float (*t)[33]) {
  const int lx = threadIdx.x & 31, ly = threadIdx.x >> 5;
  const int n0 = bx * 32, k0 = by * 32;
#pragma unroll
  for (int r = 0; r < 4; ++r) t[ly + r * 8][lx] = in[(size_t)(k0 + ly + r * 8) * N + n0 + lx];
  __syncthreads();
#pragma unroll
  for (int r = 0; r < 4; ++r)
    out[(size_t)(n0 + ly + r * 8) * K + k0 + lx] = f2bf(t[lx][ly + r * 8]);
}

__global__ __launch_bounds__(256) void prep_all(
    const float* __restrict__ emb, const float* __restrict__ Wq, const float* __restrict__ Wk,
    const float* __restrict__ Wv, const float* __restrict__ Wc, const float* __restrict__ W1,
    const float* __restrict__ W2, unsigned short* __restrict__ embB,
    unsigned short* __restrict__ WtQKV, unsigned short* __restrict__ WtC,
    unsigned short* __restrict__ Wt1, unsigned short* __restrict__ Wt2,
    float* __restrict__ maskOut) {
  __shared__ float t[32][33];
  const int blk = blockIdx.x;
  if (blk < 4096) {                       // emb f32 -> bf16, 8 B/thread
    const int i = blk * 256 + threadIdx.x;
    const float4 v = reinterpret_cast<const float4*>(emb)[i];
    s16x4 o; o[0] = f2bf(v.x); o[1] = f2bf(v.y); o[2] = f2bf(v.z); o[3] = f2bf(v.w);
    reinterpret_cast<s16x4*>(embB)[i] = o;
  } else if (blk < 4864) {                // Wq/Wk/Wv [H,D,HD] -> [(sel*512+h*64+f)][d]
    const int b = blk - 4096;
    const int bx = b & 15, by = (b >> 4) & 1, z = b >> 5;
    const int sel = z >> 3, h = z & 7;
    const float* W = sel == 0 ? Wq : (sel == 1 ? Wk : Wv);
    const float* inb = W + (size_t)h * 512 * 64;
    unsigned short* outb = WtQKV + (size_t)sel * 512 * 512 + (size_t)h * 64 * 512;
    const int lx = threadIdx.x & 31, ly = threadIdx.x >> 5;
    const int d0 = bx * 32, f0 = by * 32;
#pragma unroll
    for (int r = 0; r < 4; ++r) t[ly + r * 8][lx] = inb[(size_t)(d0 + ly + r * 8) * 64 + f0 + lx];
    __syncthreads();
#pragma unroll
    for (int r = 0; r < 4; ++r)
      outb[(size_t)(f0 + ly + r * 8) * 512 + d0 + lx] = f2bf(t[lx][ly + r * 8]);
  } else if (blk < 5120) {                // Wc [512,512] -> [N][K]
    const int b = blk - 4864;
    xpose_tile(Wc, WtC, 512, 512, b & 15, b >> 4, t);
  } else if (blk < 6144) {                // W1 [512,2048] -> [2048][512]
    const int b = blk - 5120;
    xpose_tile(W1, Wt1, 512, 2048, b & 63, b >> 6, t);
  } else if (blk < 7168) {                // W2 [2048,512] -> [512][2048]
    const int b = blk - 6144;
    xpose_tile(W2, Wt2, 2048, 512, b & 15, b >> 4, t);
  } else {                                // mask = 1.0f
    const int i = (blk - 7168) * 256 + threadIdx.x;
    if (i < Bb * Ss) maskOut[i] = 1.0f;
  }
}

// ---------- GEMM: C[M,N] = A[M,K](bf16) @ Bt[N,K]^T(bf16) ----------
// 3-buffer ring LDS pipeline, counted vmcnt, T2 swizzle, setprio, T1 XCD-chunked grid.
// EPI0 writes Q/K natural [bh][s][64] and V directly transposed [bh][64][s].
template<int EPI, int NI>
__global__ __launch_bounds__(256) void gemm_bt(
    const unsigned short* __restrict__ A, const unsigned short* __restrict__ Bt,
    const float* __restrict__ bias0, const float* __restrict__ bias1, const float* __restrict__ bias2,
    const float* __restrict__ addf, float* __restrict__ outF,
    unsigned short* __restrict__ outB0, unsigned short* __restrict__ outB1,
    unsigned short* __restrict__ outB2, int M, int N, int K, int nbx) {
  constexpr int BN = NI * 32;
  __shared__ alignas(16) unsigned short As[3][128 * 32];
  __shared__ alignas(16) unsigned short Bs[3][BN * 32];
  const int tid = threadIdx.x;
  const int lane = tid & 63, wid = tid >> 6;
  const int wr = wid >> 1, wc = wid & 1;
  const int fr = lane & 15, kg = lane >> 4;

  const int lin = blockIdx.x;
  const int xcd = lin & 7, idx = lin >> 3;
  const int bx = idx % nbx, ysub = idx / nbx;
  const int m0 = (xcd * 8 + ysub) * 128, n0 = bx * BN;

  const int srow = tid >> 2;
  const int schunk = (tid & 3) ^ ((tid >> 3) & 3);   // pre-swizzled source chunk
  const unsigned short* gA = A + (size_t)(m0 + srow) * K + (schunk << 3);
  const unsigned short* gB = Bt + (size_t)(n0 + srow) * K + (schunk << 3);

  auto STAGE = [&](int kt, int buf) {
    unsigned short* lA = &As[buf][wid * 512];
    unsigned short* lB = &Bs[buf][wid * 512];
    GLOAD_LDS16(gA + kt, lA);
    GLOAD_LDS16(gA + (size_t)64 * K + kt, lA + 2048);
    GLOAD_LDS16(gB + kt, lB);
    if constexpr (NI == 4) GLOAD_LDS16(gB + (size_t)64 * K + kt, lB + 2048);
  };

  f32x4 acc[4][NI];
#pragma unroll
  for (int i = 0; i < 4; ++i)
#pragma unroll
    for (int j = 0; j < NI; ++j)
#pragma unroll
      for (int r = 0; r < 4; ++r) acc[i][j][r] = 0.f;

  STAGE(0, 0);
  STAGE(32, 1);
  const int nk = K >> 5;
  int cur = 0;
  const int rchunk = (kg ^ ((fr >> 1) & 3)) << 3;    // swizzled read chunk (shorts)
  for (int ki = 0; ki < nk; ++ki) {
    const int pre = cur == 0 ? 2 : cur - 1;
    __builtin_amdgcn_s_barrier();
    if (ki + 2 < nk) {
      STAGE((ki + 2) << 5, pre);
      if constexpr (NI == 4)
        asm volatile("s_waitcnt vmcnt(8)" ::: "memory");
      else
        asm volatile("s_waitcnt vmcnt(6)" ::: "memory");
    } else if (ki + 1 < nk) {
      if constexpr (NI == 4)
        asm volatile("s_waitcnt vmcnt(4)" ::: "memory");
      else
        asm volatile("s_waitcnt vmcnt(3)" ::: "memory");
    } else {
      asm volatile("s_waitcnt vmcnt(0)" ::: "memory");
    }
    __builtin_amdgcn_sched_barrier(0);
    __builtin_amdgcn_s_barrier();
    __builtin_amdgcn_sched_barrier(0);

    s16x8 af[4], bfv[NI];
#pragma unroll
    for (int i = 0; i < 4; ++i)
      af[i] = *reinterpret_cast<const s16x8*>(&As[cur][(wr * 64 + i * 16 + fr) * 32 + rchunk]);
#pragma unroll
    for (int i = 0; i < NI; ++i)
      bfv[i] = *reinterpret_cast<const s16x8*>(
          &Bs[cur][(wc * (NI * 16) + i * 16 + fr) * 32 + rchunk]);
    __builtin_amdgcn_s_setprio(1);
#pragma unroll
    for (int mi = 0; mi < 4; ++mi)
#pragma unroll
      for (int ni = 0; ni < NI; ++ni)
        acc[mi][ni] = __builtin_amdgcn_mfma_f32_16x16x32_bf16(af[mi], bfv[ni], acc[mi][ni], 0, 0, 0);
    __builtin_amdgcn_s_setprio(0);
    cur = cur == 2 ? 0 : cur + 1;
  }

#pragma unroll
  for (int mi = 0; mi < 4; ++mi)
#pragma unroll
    for (int ni = 0; ni < NI; ++ni) {
      if constexpr (EPI == 0) {
        const int col = n0 + wc * (NI * 16) + ni * 16 + fr;
        const int sel = col >> 9, c = col & 511;
        const int h = c >> 6, f = c & 63;
        const int row0 = m0 + wr * 64 + mi * 16 + kg * 4;
        const int b = row0 >> 11, s0 = row0 & 2047;
        if (sel == 2) {
          const float bsv = bias2[c];
          u32x2 pk;
          pk[0] = (unsigned)f2bf(acc[mi][ni][0] + bsv) |
                  ((unsigned)f2bf(acc[mi][ni][1] + bsv) << 16);
          pk[1] = (unsigned)f2bf(acc[mi][ni][2] + bsv) |
                  ((unsigned)f2bf(acc[mi][ni][3] + bsv) << 16);
          *reinterpret_cast<u32x2*>(
              &outB2[((size_t)((b << 3) + h) * 64 + f) * 2048 + s0]) = pk;
        } else {
          const float* bs = sel == 0 ? bias0 : bias1;
          unsigned short* ob = sel == 0 ? outB0 : outB1;
          const float bv = bs[c];
#pragma unroll
          for (int r = 0; r < 4; ++r)
            ob[((size_t)((b << 3) + h) * 2048 + s0 + r) * 64 + f] =
                f2bf(acc[mi][ni][r] + bv);
        }
      } else {
#pragma unroll
        for (int r = 0; r < 4; ++r) {
          const int row = m0 + wr * 64 + mi * 16 + kg * 4 + r;
          const int col = n0 + wc * (NI * 16) + ni * 16 + fr;
          float v = acc[mi][ni][r];
          if constexpr (EPI == 1) {
            const size_t idx2 = (size_t)row * 512 + col;
            outF[idx2] = v + bias0[col] + addf[idx2];
          } else if constexpr (EPI == 2) {
            v += bias0[col];
            outB0[(size_t)row * 2048 + col] = f2bf(v > 0.f ? v : 0.f);
          } else {
            outF[(size_t)row * 512 + col] = v + bias0[col];
          }
        }
      }
    }
}

// ---------- flash attention v11: KT=128 key-tiles, 8 waves, half sync per key ----------
// grid 512 x 512thr, XCD co-location. Per 128 keys: 2 counted waits + 3 barriers
// (vs 4+6 at KT=64), one max/rescale over 32 scores. K double-buffered, V single,
// P per-wave reused across the two 64-key halves.
__global__ __launch_bounds__(512, 4) void attn_kernel(const unsigned short* __restrict__ Q,
                                                      const unsigned short* __restrict__ Kx,
                                                      const unsigned short* __restrict__ V,
                                                      unsigned short* __restrict__ Hcat) {
  const int lane = threadIdx.x & 63, wid = threadIdx.x >> 6;   // 8 waves
  const int fr = lane & 15, kg = lane >> 4;
  const int lin = blockIdx.x;
  const int xcd = lin & 7, idx = lin >> 3;
  const int bh = xcd * 4 + (idx & 3);          // 4 heads per XCD
  const int qi = idx >> 2;                     // 0..15, 128 q-rows each
  const int b = bh >> 3, h = bh & 7;
  const int q0 = qi * 128 + wid * 16;
  const unsigned short* Qh = Q + (size_t)bh * Ss * HDd;
  const unsigned short* Kh = Kx + (size_t)bh * Ss * HDd;
  const unsigned short* Vh = V + (size_t)bh * HDd * Ss;

  __shared__ alignas(16) unsigned short Ks[2][128 * 64];  // [t-row][d-col] swizzled
  __shared__ alignas(16) unsigned short Vs[64 * 128];     // [d-row][t-col] swizzled (16 chunks/row)
  __shared__ alignas(16) unsigned short P[8][16][72];     // per-wave [q][t-half]

  // K staging: 2 instr/wave, 8 rows (128B) each; rows [i*64 + wid*8 + srow]
  const int srow = lane >> 3;
  const int scolK = ((lane & 7) ^ srow) << 3;  // shorts, inverse swizzle on source
  const unsigned short* gK0 = Kh + (size_t)(8 * wid + srow) * 64 + scolK;
  const unsigned short* gK1 = Kh + (size_t)(64 + 8 * wid + srow) * 64 + scolK;
  unsigned short* lK0a = &Ks[0][wid * 512];
  unsigned short* lK1a = &Ks[0][4096 + wid * 512];
  unsigned short* lK0b = &Ks[1][wid * 512];
  unsigned short* lK1b = &Ks[1][4096 + wid * 512];

  // V staging: 2 instr/wave, 4 rows (256B) each; rows [i*32 + wid*4 + (lane>>4)]
  const int vrow = wid * 4 + (lane >> 4);
  const int scolV = ((lane & 15) ^ (vrow & 7)) << 3;      // (vrow+32)&7 == vrow&7
  const unsigned short* gV0 = Vh + (size_t)vrow * 2048 + scolV;
  const unsigned short* gV1 = Vh + (size_t)(32 + vrow) * 2048 + scolV;
  unsigned short* lV0 = &Vs[wid * 512];
  unsigned short* lV1 = &Vs[4096 + wid * 512];

  // Q as B-fragment: col=q=fr, k=kg*8+j
  s16x8 bq[2];
#pragma unroll
  for (int kb = 0; kb < 2; ++kb)
    bq[kb] = *reinterpret_cast<const s16x8*>(&Qh[(size_t)(q0 + fr) * 64 + kb * 32 + kg * 8]);

  f32x4 o[4];          // D[q = kg*4+r][d = ct*16+fr]
#pragma unroll
  for (int ct = 0; ct < 4; ++ct)
#pragma unroll
    for (int r = 0; r < 4; ++r) o[ct][r] = 0.f;
  float mr = -1e30f, lsum = 0.f;   // softmax state for q-row = fr (log2 units)

  const float iscL = 1.4426950408889634f * 0.044194173824159216f; // log2(e)/sqrt(512)
  const int swz = (fr & 7) << 3;   // read-side XOR (shorts)

  // prologue: stage K(0) then V(0)
  GLOAD_LDS16(gK0, lK0a);
  GLOAD_LDS16(gK1, lK1a);
  GLOAD_LDS16(gV0, lV0);
  GLOAD_LDS16(gV1, lV1);

#pragma unroll 1
  for (int t = 0; t < 16; ++t) {
    const int ktn = (t * 128 + 128) & 2047;      // wraps (dummy stage) at t=15
    const unsigned short* KsC = Ks[t & 1];
    unsigned short* nK0 = (t & 1) ? lK0a : lK0b;
    unsigned short* nK1 = (t & 1) ? lK1a : lK1b;

    // wait my K(t) (2 oldest of [K:2, V:2]); barrier -> all waves' K landed,
    // and all waves finished reading Ks[cur^1] during iter t-1.
    asm volatile("s_waitcnt vmcnt(2)" ::: "memory");
    __builtin_amdgcn_sched_barrier(0);
    __builtin_amdgcn_s_barrier();
    __builtin_amdgcn_sched_barrier(0);

    // issue K(t+1) (full-iteration issue-to-use distance)
    GLOAD_LDS16(gK0 + (size_t)ktn * 64, nK0);
    GLOAD_LDS16(gK1 + (size_t)ktn * 64, nK1);

    // QK^T swapped over 128 keys: lane holds q=fr, t' = ctg*16 + kg*4 + r
    f32x4 sc[8];
#pragma unroll
    for (int ctg = 0; ctg < 8; ++ctg)
#pragma unroll
      for (int r = 0; r < 4; ++r) sc[ctg][r] = 0.f;
    __builtin_amdgcn_s_setprio(1);
#pragma unroll
    for (int ctg = 0; ctg < 8; ++ctg)
#pragma unroll
      for (int kb = 0; kb < 2; ++kb) {
        const s16x8 kf = *reinterpret_cast<const s16x8*>(
            &KsC[(ctg * 16 + fr) * 64 + (((kg << 3) + (kb << 5)) ^ swz)]);
        sc[ctg] = __builtin_amdgcn_mfma_f32_16x16x32_bf16(kf, bq[kb], sc[ctg], 0, 0, 0);
      }
    __builtin_amdgcn_s_setprio(0);

    // lane-local max over 32 scores (scaled units)
    float mxl;
    {
      float a[8];
#pragma unroll
      for (int ctg = 0; ctg < 8; ++ctg)
        a[ctg] = fmaxf(fmaxf(sc[ctg][0], sc[ctg][1]), fmaxf(sc[ctg][2], sc[ctg][3]));
      const float b0 = fmaxf(fmaxf(a[0], a[1]), fmaxf(a[2], a[3]));
      const float b1 = fmaxf(fmaxf(a[4], a[5]), fmaxf(a[6], a[7]));
      mxl = fmaxf(b0, b1) * iscL;
    }
    // defer-max (T13): rescale only when some lane's max grew past mr+8 (wave-uniform)
    if (!__all(mxl <= mr + 8.0f)) {
      float mx = fmaxf(mxl, __shfl_xor(mxl, 16));
      mx = fmaxf(mx, __shfl_xor(mx, 32));
      const float mn = fmaxf(mr, mx);
      const float corr = exp2_raw(mr - mn);
      mr = mn;
      lsum *= corr;
      float corrq[4];
#pragma unroll
      for (int r = 0; r < 4; ++r) corrq[r] = __shfl(corr, kg * 4 + r);
#pragma unroll
      for (int ct = 0; ct < 4; ++ct)
#pragma unroll
        for (int r = 0; r < 4; ++r) o[ct][r] *= corrq[r];
    }

    // wait my V(t) ([V:2 oldest, K(t+1):2] -> vmcnt(2)); barrier -> everyone's V ready
    asm volatile("s_waitcnt vmcnt(2)" ::: "memory");
    __builtin_amdgcn_sched_barrier(0);
    __builtin_amdgcn_s_barrier();
    __builtin_amdgcn_sched_barrier(0);

    // two 64-key halves: P pack (per-wave LDS, reused) then PV
#pragma unroll
    for (int half = 0; half < 2; ++half) {
      float ps0 = 0.f, ps1 = 0.f;
#pragma unroll
      for (int ctl = 0; ctl < 4; ++ctl) {
        const int ctg = half * 4 + ctl;
        float p0 = exp2_raw(__builtin_fmaf(sc[ctg][0], iscL, -mr));
        float p1 = exp2_raw(__builtin_fmaf(sc[ctg][1], iscL, -mr));
        float p2 = exp2_raw(__builtin_fmaf(sc[ctg][2], iscL, -mr));
        float p3 = exp2_raw(__builtin_fmaf(sc[ctg][3], iscL, -mr));
        ps0 += (p0 + p1);
        ps1 += (p2 + p3);
        u32x2 pk;
        pk[0] = cvt_pk_bf16(p0, p1);
        pk[1] = cvt_pk_bf16(p2, p3);
        *reinterpret_cast<u32x2*>(&P[wid][fr][ctl * 16 + kg * 4]) = pk;
      }
      lsum += ps0 + ps1;

      const s16x8 pa0 = *reinterpret_cast<const s16x8*>(&P[wid][fr][kg * 8]);
      const s16x8 pa1 = *reinterpret_cast<const s16x8*>(&P[wid][fr][32 + kg * 8]);
      __builtin_amdgcn_s_setprio(1);
#pragma unroll
      for (int ct = 0; ct < 4; ++ct) {
        const s16x8 bv0 = *reinterpret_cast<const s16x8*>(
            &Vs[(ct * 16 + fr) * 128 + ((half * 64 + kg * 8) ^ swz)]);
        o[ct] = __builtin_amdgcn_mfma_f32_16x16x32_bf16(pa0, bv0, o[ct], 0, 0, 0);
        const s16x8 bv1 = *reinterpret_cast<const s16x8*>(
            &Vs[(ct * 16 + fr) * 128 + ((half * 64 + 32 + kg * 8) ^ swz)]);
        o[ct] = __builtin_amdgcn_mfma_f32_16x16x32_bf16(pa1, bv1, o[ct], 0, 0, 0);
      }
      __builtin_amdgcn_s_setprio(0);
    }

    // all PV reads of Vs done -> safe to overwrite; issue V(t+1) stage
    __builtin_amdgcn_s_barrier();
    __builtin_amdgcn_sched_barrier(0);
    GLOAD_LDS16(gV0 + ktn, lV0);
    GLOAD_LDS16(gV1 + ktn, lV1);
  }

  lsum += __shfl_xor(lsum, 16);
  lsum += __shfl_xor(lsum, 32);
  float invq[4];
#pragma unroll
  for (int r = 0; r < 4; ++r) invq[r] = 1.0f / __shfl(lsum, kg * 4 + r);
#pragma unroll
  for (int ct = 0; ct < 4; ++ct)
#pragma unroll
    for (int r = 0; r < 4; ++r) {
      const int qrow = q0 + kg * 4 + r;
      Hcat[(size_t)(b * Ss + qrow) * Dd + h * 64 + ct * 16 + fr] = f2bf(o[ct][r] * invq[r]);
    }
}

// ---------- LayerNorm: one wave per row of 512 ----------
__global__ __launch_bounds__(256) void layernorm_k(const float* __restrict__ res,
                                                   const float* __restrict__ gamma,
                                                   const float* __restrict__ beta,
                                                   unsigned short* __restrict__ out) {
  const int lane = threadIdx.x & 63, wid = threadIdx.x >> 6;
  const int row = blockIdx.x * 4 + wid;
  const float* rp = res + (size_t)row * 512 + lane * 8;
  const float4 v0 = *reinterpret_cast<const float4*>(rp);
  const float4 v1 = *reinterpret_cast<const float4*>(rp + 4);
  float x[8] = {v0.x, v0.y, v0.z, v0.w, v1.x, v1.y, v1.z, v1.w};
  float s = 0.f, q = 0.f;
#pragma unroll
  for (int j = 0; j < 8; ++j) { s += x[j]; q += x[j] * x[j]; }
#pragma unroll
  for (int off = 32; off; off >>= 1) { s += __shfl_xor(s, off); q += __shfl_xor(q, off); }
  const float mean = s * (1.f / 512.f);
  const float var = q * (1.f / 512.f) - mean * mean;
  const float rstd = rsqrtf(var + 1e-5f);
  s16x8 o;
#pragma unroll
  for (int j = 0; j < 8; ++j) {
    const int c = lane * 8 + j;
    o[j] = f2bf((x[j] - mean) * rstd * gamma[c] + beta[c]);
  }
  *reinterpret_cast<s16x8*>(out + (size_t)row * 512 + lane * 8) = o;
}

extern "C" void kernel_launch(void* const* d_in, const int* in_sizes, int n_in,
                              void* d_out, int out_size, void* d_ws, size_t ws_size,
                              hipStream_t stream) {
  const float* emb = (const float*)d_in[0];
  const float* Wq = (const float*)d_in[2];
  const float* bq = (const float*)d_in[3];
  const float* Wk = (const float*)d_in[4];
  const float* bk = (const float*)d_in[5];
  const float* Wv = (const float*)d_in[6];
  const float* bv = (const float*)d_in[7];
  const float* Wc = (const float*)d_in[8];
  const float* bc = (const float*)d_in[9];
  const float* W1 = (const float*)d_in[10];
  const float* b1 = (const float*)d_in[11];
  const float* W2 = (const float*)d_in[12];
  const float* b2 = (const float*)d_in[13];
  const float* gamma = (const float*)d_in[14];
  const float* beta = (const float*)d_in[15];
  float* out = (float*)d_out;

  char* ws = (char*)d_ws;
  size_t off = 0;
  auto alloc = [&](size_t bytes) {
    char* p = ws + off;
    off = (off + bytes + 255) & ~(size_t)255;
    return p;
  };
  unsigned short* embB = (unsigned short*)alloc((size_t)Mm * Dd * 2);
  unsigned short* WtQKV = (unsigned short*)alloc((size_t)1536 * 512 * 2);
  unsigned short* WtC = (unsigned short*)alloc((size_t)512 * 512 * 2);
  unsigned short* Wt1 = (unsigned short*)alloc((size_t)2048 * 512 * 2);
  unsigned short* Wt2 = (unsigned short*)alloc((size_t)512 * 2048 * 2);
  unsigned short* Qb = (unsigned short*)alloc((size_t)Mm * Dd * 2);
  unsigned short* Kb = (unsigned short*)alloc((size_t)Mm * Dd * 2);
  unsigned short* Vt = (unsigned short*)alloc((size_t)Mm * Dd * 2);
  unsigned short* Hcat = (unsigned short*)alloc((size_t)Mm * Dd * 2);
  float* resF = (float*)alloc((size_t)Mm * Dd * 4);
  unsigned short* HnB = (unsigned short*)alloc((size_t)Mm * Dd * 2);
  unsigned short* G = Qb;   // reuse: dead after proj GEMM

  prep_all<<<7200, 256, 0, stream>>>(emb, Wq, Wk, Wv, Wc, W1, W2,
                                     embB, WtQKV, WtC, Wt1, Wt2,
                                     out + (size_t)Mm * Dd);

  gemm_bt<0, 4><<<768, 256, 0, stream>>>(embB, WtQKV, bq, bk, bv, nullptr, nullptr,
                                         Qb, Kb, Vt, Mm, 1536, 512, 12);
  attn_kernel<<<512, 512, 0, stream>>>(Qb, Kb, Vt, Hcat);
  gemm_bt<1, 2><<<512, 256, 0, stream>>>(Hcat, WtC, bc, nullptr, nullptr, emb, resF,
                                         nullptr, nullptr, nullptr, Mm, 512, 512, 8);
  layernorm_k<<<2048, 256, 0, stream>>>(resF, gamma, beta, HnB);
  gemm_bt<2, 4><<<1024, 256, 0, stream>>>(HnB, Wt1, b1, nullptr, nullptr, nullptr, nullptr,
                                          G, nullptr, nullptr, Mm, 2048, 512, 16);
  gemm_bt<3, 2><<<512, 256, 0, stream>>>(G, Wt2, b2, nullptr, nullptr, nullptr, out,
                                         nullptr, nullptr, nullptr, Mm, 512, 2048, 8);
}

// Round 17
// 166.958 us; speedup vs baseline: 1.0213x; 1.0213x over previous
//
#include <hip/hip_runtime.h>
#include <hip/hip_bf16.h>
#include <cstdint>
#include <cstddef>

typedef short  s16x8 __attribute__((ext_vector_type(8)));
typedef short  s16x4 __attribute__((ext_vector_type(4)));
typedef float  f32x4 __attribute__((ext_vector_type(4)));
typedef unsigned u32x2 __attribute__((ext_vector_type(2)));

static constexpr int Bb = 4, Ss = 2048, Dd = 512, Hh = 8, HDd = 64, FFf = 2048;
static constexpr int Mm = Bb * Ss; // 8192

__device__ __forceinline__ unsigned short f2bf(float f) {
  unsigned u = __float_as_uint(f);
  u += 0x7FFFu + ((u >> 16) & 1u);   // RNE
  return (unsigned short)(u >> 16);
}

__device__ __forceinline__ unsigned cvt_pk_bf16(float lo, float hi) {
  unsigned r;
  asm("v_cvt_pk_bf16_f32 %0, %1, %2" : "=v"(r) : "v"(lo), "v"(hi));
  return r;
}

// raw hardware exp2 (inputs bounded by defer-max; underflow->0 is desired)
__device__ __forceinline__ float exp2_raw(float x) {
  float r;
  asm("v_exp_f32 %0, %1\n\ts_nop 0" : "=v"(r) : "v"(x));
  return r;
}

#define GLOAD_LDS16(gp, lp)                                                     \
  __builtin_amdgcn_global_load_lds((const __attribute__((address_space(1))) void*)(gp), \
                                   (__attribute__((address_space(3))) void*)(lp), 16, 0, 0)

// ---------- fused prep: emb cvt + QKV weight prep + 3 transposes + mask ----------
__device__ __forceinline__ void xpose_tile(const float* __restrict__ in,
                                           unsigned short* __restrict__ out,
                                           int K, int N, int bx, int by, float (*t)[33]) {
  const int lx = threadIdx.x & 31, ly = threadIdx.x >> 5;
  const int n0 = bx * 32, k0 = by * 32;
#pragma unroll
  for (int r = 0; r < 4; ++r) t[ly + r * 8][lx] = in[(size_t)(k0 + ly + r * 8) * N + n0 + lx];
  __syncthreads();
#pragma unroll
  for (int r = 0; r < 4; ++r)
    out[(size_t)(n0 + ly + r * 8) * K + k0 + lx] = f2bf(t[lx][ly + r * 8]);
}

__global__ __launch_bounds__(256) void prep_all(
    const float* __restrict__ emb, const float* __restrict__ Wq, const float* __restrict__ Wk,
    const float* __restrict__ Wv, const float* __restrict__ Wc, const float* __restrict__ W1,
    const float* __restrict__ W2, unsigned short* __restrict__ embB,
    unsigned short* __restrict__ WtQKV, unsigned short* __restrict__ WtC,
    unsigned short* __restrict__ Wt1, unsigned short* __restrict__ Wt2,
    float* __restrict__ maskOut) {
  __shared__ float t[32][33];
  const int blk = blockIdx.x;
  if (blk < 4096) {                       // emb f32 -> bf16, 8 B/thread
    const int i = blk * 256 + threadIdx.x;
    const float4 v = reinterpret_cast<const float4*>(emb)[i];
    s16x4 o; o[0] = f2bf(v.x); o[1] = f2bf(v.y); o[2] = f2bf(v.z); o[3] = f2bf(v.w);
    reinterpret_cast<s16x4*>(embB)[i] = o;
  } else if (blk < 4864) {                // Wq/Wk/Wv [H,D,HD] -> [(sel*512+h*64+f)][d]
    const int b = blk - 4096;
    const int bx = b & 15, by = (b >> 4) & 1, z = b >> 5;
    const int sel = z >> 3, h = z & 7;
    const float* W = sel == 0 ? Wq : (sel == 1 ? Wk : Wv);
    const float* inb = W + (size_t)h * 512 * 64;
    unsigned short* outb = WtQKV + (size_t)sel * 512 * 512 + (size_t)h * 64 * 512;
    const int lx = threadIdx.x & 31, ly = threadIdx.x >> 5;
    const int d0 = bx * 32, f0 = by * 32;
#pragma unroll
    for (int r = 0; r < 4; ++r) t[ly + r * 8][lx] = inb[(size_t)(d0 + ly + r * 8) * 64 + f0 + lx];
    __syncthreads();
#pragma unroll
    for (int r = 0; r < 4; ++r)
      outb[(size_t)(f0 + ly + r * 8) * 512 + d0 + lx] = f2bf(t[lx][ly + r * 8]);
  } else if (blk < 5120) {                // Wc [512,512] -> [N][K]
    const int b = blk - 4864;
    xpose_tile(Wc, WtC, 512, 512, b & 15, b >> 4, t);
  } else if (blk < 6144) {                // W1 [512,2048] -> [2048][512]
    const int b = blk - 5120;
    xpose_tile(W1, Wt1, 512, 2048, b & 63, b >> 6, t);
  } else if (blk < 7168) {                // W2 [2048,512] -> [512][2048]
    const int b = blk - 6144;
    xpose_tile(W2, Wt2, 2048, 512, b & 15, b >> 4, t);
  } else {                                // mask = 1.0f
    const int i = (blk - 7168) * 256 + threadIdx.x;
    if (i < Bb * Ss) maskOut[i] = 1.0f;
  }
}

// ---------- GEMM: C[M,N] = A[M,K](bf16) @ Bt[N,K]^T(bf16) ----------
// 3-buffer ring LDS pipeline, counted vmcnt, T2 swizzle, setprio, T1 XCD-chunked grid.
// EPI0 writes Q/K natural [bh][s][64] and V directly transposed [bh][64][s].
template<int EPI, int NI>
__global__ __launch_bounds__(256) void gemm_bt(
    const unsigned short* __restrict__ A, const unsigned short* __restrict__ Bt,
    const float* __restrict__ bias0, const float* __restrict__ bias1, const float* __restrict__ bias2,
    const float* __restrict__ addf, float* __restrict__ outF,
    unsigned short* __restrict__ outB0, unsigned short* __restrict__ outB1,
    unsigned short* __restrict__ outB2, int M, int N, int K, int nbx) {
  constexpr int BN = NI * 32;
  __shared__ alignas(16) unsigned short As[3][128 * 32];
  __shared__ alignas(16) unsigned short Bs[3][BN * 32];
  const int tid = threadIdx.x;
  const int lane = tid & 63, wid = tid >> 6;
  const int wr = wid >> 1, wc = wid & 1;
  const int fr = lane & 15, kg = lane >> 4;

  const int lin = blockIdx.x;
  const int xcd = lin & 7, idx = lin >> 3;
  const int bx = idx % nbx, ysub = idx / nbx;
  const int m0 = (xcd * 8 + ysub) * 128, n0 = bx * BN;

  const int srow = tid >> 2;
  const int schunk = (tid & 3) ^ ((tid >> 3) & 3);   // pre-swizzled source chunk
  const unsigned short* gA = A + (size_t)(m0 + srow) * K + (schunk << 3);
  const unsigned short* gB = Bt + (size_t)(n0 + srow) * K + (schunk << 3);

  auto STAGE = [&](int kt, int buf) {
    unsigned short* lA = &As[buf][wid * 512];
    unsigned short* lB = &Bs[buf][wid * 512];
    GLOAD_LDS16(gA + kt, lA);
    GLOAD_LDS16(gA + (size_t)64 * K + kt, lA + 2048);
    GLOAD_LDS16(gB + kt, lB);
    if constexpr (NI == 4) GLOAD_LDS16(gB + (size_t)64 * K + kt, lB + 2048);
  };

  f32x4 acc[4][NI];
#pragma unroll
  for (int i = 0; i < 4; ++i)
#pragma unroll
    for (int j = 0; j < NI; ++j)
#pragma unroll
      for (int r = 0; r < 4; ++r) acc[i][j][r] = 0.f;

  STAGE(0, 0);
  STAGE(32, 1);
  const int nk = K >> 5;
  int cur = 0;
  const int rchunk = (kg ^ ((fr >> 1) & 3)) << 3;    // swizzled read chunk (shorts)
  for (int ki = 0; ki < nk; ++ki) {
    const int pre = cur == 0 ? 2 : cur - 1;
    __builtin_amdgcn_s_barrier();
    if (ki + 2 < nk) {
      STAGE((ki + 2) << 5, pre);
      if constexpr (NI == 4)
        asm volatile("s_waitcnt vmcnt(8)" ::: "memory");
      else
        asm volatile("s_waitcnt vmcnt(6)" ::: "memory");
    } else if (ki + 1 < nk) {
      if constexpr (NI == 4)
        asm volatile("s_waitcnt vmcnt(4)" ::: "memory");
      else
        asm volatile("s_waitcnt vmcnt(3)" ::: "memory");
    } else {
      asm volatile("s_waitcnt vmcnt(0)" ::: "memory");
    }
    __builtin_amdgcn_sched_barrier(0);
    __builtin_amdgcn_s_barrier();
    __builtin_amdgcn_sched_barrier(0);

    s16x8 af[4], bfv[NI];
#pragma unroll
    for (int i = 0; i < 4; ++i)
      af[i] = *reinterpret_cast<const s16x8*>(&As[cur][(wr * 64 + i * 16 + fr) * 32 + rchunk]);
#pragma unroll
    for (int i = 0; i < NI; ++i)
      bfv[i] = *reinterpret_cast<const s16x8*>(
          &Bs[cur][(wc * (NI * 16) + i * 16 + fr) * 32 + rchunk]);
    __builtin_amdgcn_s_setprio(1);
#pragma unroll
    for (int mi = 0; mi < 4; ++mi)
#pragma unroll
      for (int ni = 0; ni < NI; ++ni)
        acc[mi][ni] = __builtin_amdgcn_mfma_f32_16x16x32_bf16(af[mi], bfv[ni], acc[mi][ni], 0, 0, 0);
    __builtin_amdgcn_s_setprio(0);
    cur = cur == 2 ? 0 : cur + 1;
  }

#pragma unroll
  for (int mi = 0; mi < 4; ++mi)
#pragma unroll
    for (int ni = 0; ni < NI; ++ni) {
      if constexpr (EPI == 0) {
        const int col = n0 + wc * (NI * 16) + ni * 16 + fr;
        const int sel = col >> 9, c = col & 511;
        const int h = c >> 6, f = c & 63;
        const int row0 = m0 + wr * 64 + mi * 16 + kg * 4;
        const int b = row0 >> 11, s0 = row0 & 2047;
        if (sel == 2) {
          const float bsv = bias2[c];
          u32x2 pk;
          pk[0] = (unsigned)f2bf(acc[mi][ni][0] + bsv) |
                  ((unsigned)f2bf(acc[mi][ni][1] + bsv) << 16);
          pk[1] = (unsigned)f2bf(acc[mi][ni][2] + bsv) |
                  ((unsigned)f2bf(acc[mi][ni][3] + bsv) << 16);
          *reinterpret_cast<u32x2*>(
              &outB2[((size_t)((b << 3) + h) * 64 + f) * 2048 + s0]) = pk;
        } else {
          const float* bs = sel == 0 ? bias0 : bias1;
          unsigned short* ob = sel == 0 ? outB0 : outB1;
          const float bv = bs[c];
#pragma unroll
          for (int r = 0; r < 4; ++r)
            ob[((size_t)((b << 3) + h) * 2048 + s0 + r) * 64 + f] =
                f2bf(acc[mi][ni][r] + bv);
        }
      } else {
#pragma unroll
        for (int r = 0; r < 4; ++r) {
          const int row = m0 + wr * 64 + mi * 16 + kg * 4 + r;
          const int col = n0 + wc * (NI * 16) + ni * 16 + fr;
          float v = acc[mi][ni][r];
          if constexpr (EPI == 1) {
            const size_t idx2 = (size_t)row * 512 + col;
            outF[idx2] = v + bias0[col] + addf[idx2];
          } else if constexpr (EPI == 2) {
            v += bias0[col];
            outB0[(size_t)row * 2048 + col] = f2bf(v > 0.f ? v : 0.f);
          } else {
            outF[(size_t)row * 512 + col] = v + bias0[col];
          }
        }
      }
    }
}

// ---------- flash attention v12: KT=64, 8 waves, K+V double-buffered,
// SINGLE barrier + SINGLE vmcnt(0) per tile (full-iteration issue-to-use cover).
// Occupancy-neutral vs r15 (grid 512 -> 2 blocks/CU for any LDS <= 80KB). ----------
__global__ __launch_bounds__(512) void attn_kernel(const unsigned short* __restrict__ Q,
                                                   const unsigned short* __restrict__ Kx,
                                                   const unsigned short* __restrict__ V,
                                                   unsigned short* __restrict__ Hcat) {
  const int lane = threadIdx.x & 63, wid = threadIdx.x >> 6;   // 8 waves
  const int fr = lane & 15, kg = lane >> 4;
  const int lin = blockIdx.x;
  const int xcd = lin & 7, idx = lin >> 3;
  const int bh = xcd * 4 + (idx & 3);          // 4 heads per XCD
  const int qi = idx >> 2;                     // 0..15, 128 q-rows each
  const int b = bh >> 3, h = bh & 7;
  const int q0 = qi * 128 + wid * 16;
  const unsigned short* Qh = Q + (size_t)bh * Ss * HDd;
  const unsigned short* Kh = Kx + (size_t)bh * Ss * HDd;
  const unsigned short* Vh = V + (size_t)bh * HDd * Ss;

  __shared__ alignas(16) unsigned short Ks[2][64 * 64];  // [t-row][d-col] swizzled
  __shared__ alignas(16) unsigned short Vs[2][64 * 64];  // [d-row][t-col] swizzled
  __shared__ alignas(16) unsigned short P[8][16][72];    // per-wave [q][t]

  const int srow = lane >> 3;
  const int scol = ((lane & 7) ^ srow) << 3;  // shorts, inverse swizzle on source
  // each wave stages 8 rows with ONE instruction per tile (K and V each)
  const unsigned short* gK = Kh + (size_t)(8 * wid + srow) * 64 + scol;
  const unsigned short* gV = Vh + (size_t)(8 * wid + srow) * 2048 + scol;
  unsigned short* lKa = &Ks[0][wid * 512];
  unsigned short* lKb = &Ks[1][wid * 512];
  unsigned short* lVa = &Vs[0][wid * 512];
  unsigned short* lVb = &Vs[1][wid * 512];

  // Q as B-fragment: col=q=fr, k=kg*8+j
  s16x8 bq[2];
#pragma unroll
  for (int kb = 0; kb < 2; ++kb)
    bq[kb] = *reinterpret_cast<const s16x8*>(&Qh[(size_t)(q0 + fr) * 64 + kb * 32 + kg * 8]);

  f32x4 o[4];          // D[q = kg*4+r][d = ct*16+fr]
#pragma unroll
  for (int ct = 0; ct < 4; ++ct)
#pragma unroll
    for (int r = 0; r < 4; ++r) o[ct][r] = 0.f;
  float mr = -1e30f, lsum = 0.f;   // softmax state for q-row = fr (log2 units)

  const float iscL = 1.4426950408889634f * 0.044194173824159216f; // log2(e)/sqrt(512)
  const int swz = (fr & 7) << 3;   // read-side XOR (shorts)

  // prologue: stage K(0), V(0) into buffer 0
  GLOAD_LDS16(gK, lKa);
  GLOAD_LDS16(gV, lVa);

#pragma unroll 1
  for (int t = 0; t < 32; ++t) {
    const int cur = t & 1;
    const int ktn = (t * 64 + 64) & 2047;        // wraps (dummy stage) at t=31

    // (1) my K(t),V(t) landed (issued a full iteration ago -> covered);
    // (2) barrier => all waves' stage(t) landed AND all waves finished reading
    //     the cur^1 buffers during tile t-1 -> restaging them is race-free.
    asm volatile("s_waitcnt vmcnt(0)" ::: "memory");
    __builtin_amdgcn_sched_barrier(0);
    __builtin_amdgcn_s_barrier();
    __builtin_amdgcn_sched_barrier(0);

    // issue stage(t+1) into cur^1; stays in flight across this tile's compute
    GLOAD_LDS16(gK + (size_t)ktn * 64, cur ? lKa : lKb);
    GLOAD_LDS16(gV + ktn, cur ? lVa : lVb);

    // QK^T swapped: D[t'][q], lane holds q=fr, t' = ct*16 + kg*4 + r
    f32x4 sc[4];
#pragma unroll
    for (int ct = 0; ct < 4; ++ct)
#pragma unroll
      for (int r = 0; r < 4; ++r) sc[ct][r] = 0.f;
    __builtin_amdgcn_s_setprio(1);
#pragma unroll
    for (int ct = 0; ct < 4; ++ct)
#pragma unroll
      for (int kb = 0; kb < 2; ++kb) {
        const s16x8 kf = *reinterpret_cast<const s16x8*>(
            &Ks[cur][(ct * 16 + fr) * 64 + (((kg << 3) + (kb << 5)) ^ swz)]);
        sc[ct] = __builtin_amdgcn_mfma_f32_16x16x32_bf16(kf, bq[kb], sc[ct], 0, 0, 0);
      }
    __builtin_amdgcn_s_setprio(0);

    // lane-local max over this lane's 16 scores (scaled units)
    float mxl;
    {
      const float a0 = fmaxf(fmaxf(sc[0][0], sc[0][1]), fmaxf(sc[0][2], sc[0][3]));
      const float a1 = fmaxf(fmaxf(sc[1][0], sc[1][1]), fmaxf(sc[1][2], sc[1][3]));
      const float a2 = fmaxf(fmaxf(sc[2][0], sc[2][1]), fmaxf(sc[2][2], sc[2][3]));
      const float a3 = fmaxf(fmaxf(sc[3][0], sc[3][1]), fmaxf(sc[3][2], sc[3][3]));
      mxl = fmaxf(fmaxf(a0, a1), fmaxf(a2, a3)) * iscL;
    }
    // defer-max (T13): rescale only when some lane's max grew past mr+8 (wave-uniform)
    if (!__all(mxl <= mr + 8.0f)) {
      float mx = fmaxf(mxl, __shfl_xor(mxl, 16));
      mx = fmaxf(mx, __shfl_xor(mx, 32));
      const float mn = fmaxf(mr, mx);
      const float corr = exp2_raw(mr - mn);
      mr = mn;
      lsum *= corr;
      float corrq[4];
#pragma unroll
      for (int r = 0; r < 4; ++r) corrq[r] = __shfl(corr, kg * 4 + r);
#pragma unroll
      for (int ct = 0; ct < 4; ++ct)
#pragma unroll
        for (int r = 0; r < 4; ++r) o[ct][r] *= corrq[r];
    }

    // P = exp2(sc*iscL - mr), bounded by 2^8; raw v_exp + v_cvt_pk_bf16_f32
    float ps0 = 0.f, ps1 = 0.f;
#pragma unroll
    for (int ct = 0; ct < 4; ++ct) {
      float p0 = exp2_raw(__builtin_fmaf(sc[ct][0], iscL, -mr));
      float p1 = exp2_raw(__builtin_fmaf(sc[ct][1], iscL, -mr));
      float p2 = exp2_raw(__builtin_fmaf(sc[ct][2], iscL, -mr));
      float p3 = exp2_raw(__builtin_fmaf(sc[ct][3], iscL, -mr));
      ps0 += (p0 + p1);
      ps1 += (p2 + p3);
      u32x2 pk;
      pk[0] = cvt_pk_bf16(p0, p1);
      pk[1] = cvt_pk_bf16(p2, p3);
      *reinterpret_cast<u32x2*>(&P[wid][fr][ct * 16 + kg * 4]) = pk;
    }
    lsum += ps0 + ps1;

    // PV: P per-wave (compiler lgkm-orders); Vs[cur] proven ready by top barrier.
    const s16x8 pa0 = *reinterpret_cast<const s16x8*>(&P[wid][fr][kg * 8]);
    const s16x8 pa1 = *reinterpret_cast<const s16x8*>(&P[wid][fr][32 + kg * 8]);
    __builtin_amdgcn_s_setprio(1);
#pragma unroll
    for (int ct = 0; ct < 4; ++ct) {
      const s16x8 bv0 = *reinterpret_cast<const s16x8*>(
          &Vs[cur][(ct * 16 + fr) * 64 + (((kg << 3) + 0) ^ swz)]);
      o[ct] = __builtin_amdgcn_mfma_f32_16x16x32_bf16(pa0, bv0, o[ct], 0, 0, 0);
      const s16x8 bv1 = *reinterpret_cast<const s16x8*>(
          &Vs[cur][(ct * 16 + fr) * 64 + (((kg << 3) + 32) ^ swz)]);
      o[ct] = __builtin_amdgcn_mfma_f32_16x16x32_bf16(pa1, bv1, o[ct], 0, 0, 0);
    }
    __builtin_amdgcn_s_setprio(0);
  }

  lsum += __shfl_xor(lsum, 16);
  lsum += __shfl_xor(lsum, 32);
  float invq[4];
#pragma unroll
  for (int r = 0; r < 4; ++r) invq[r] = 1.0f / __shfl(lsum, kg * 4 + r);
#pragma unroll
  for (int ct = 0; ct < 4; ++ct)
#pragma unroll
    for (int r = 0; r < 4; ++r) {
      const int qrow = q0 + kg * 4 + r;
      Hcat[(size_t)(b * Ss + qrow) * Dd + h * 64 + ct * 16 + fr] = f2bf(o[ct][r] * invq[r]);
    }
}

// ---------- LayerNorm: one wave per row of 512 ----------
__global__ __launch_bounds__(256) void layernorm_k(const float* __restrict__ res,
                                                   const float* __restrict__ gamma,
                                                   const float* __restrict__ beta,
                                                   unsigned short* __restrict__ out) {
  const int lane = threadIdx.x & 63, wid = threadIdx.x >> 6;
  const int row = blockIdx.x * 4 + wid;
  const float* rp = res + (size_t)row * 512 + lane * 8;
  const float4 v0 = *reinterpret_cast<const float4*>(rp);
  const float4 v1 = *reinterpret_cast<const float4*>(rp + 4);
  float x[8] = {v0.x, v0.y, v0.z, v0.w, v1.x, v1.y, v1.z, v1.w};
  float s = 0.f, q = 0.f;
#pragma unroll
  for (int j = 0; j < 8; ++j) { s += x[j]; q += x[j] * x[j]; }
#pragma unroll
  for (int off = 32; off; off >>= 1) { s += __shfl_xor(s, off); q += __shfl_xor(q, off); }
  const float mean = s * (1.f / 512.f);
  const float var = q * (1.f / 512.f) - mean * mean;
  const float rstd = rsqrtf(var + 1e-5f);
  s16x8 o;
#pragma unroll
  for (int j = 0; j < 8; ++j) {
    const int c = lane * 8 + j;
    o[j] = f2bf((x[j] - mean) * rstd * gamma[c] + beta[c]);
  }
  *reinterpret_cast<s16x8*>(out + (size_t)row * 512 + lane * 8) = o;
}

extern "C" void kernel_launch(void* const* d_in, const int* in_sizes, int n_in,
                              void* d_out, int out_size, void* d_ws, size_t ws_size,
                              hipStream_t stream) {
  const float* emb = (const float*)d_in[0];
  const float* Wq = (const float*)d_in[2];
  const float* bq = (const float*)d_in[3];
  const float* Wk = (const float*)d_in[4];
  const float* bk = (const float*)d_in[5];
  const float* Wv = (const float*)d_in[6];
  const float* bv = (const float*)d_in[7];
  const float* Wc = (const float*)d_in[8];
  const float* bc = (const float*)d_in[9];
  const float* W1 = (const float*)d_in[10];
  const float* b1 = (const float*)d_in[11];
  const float* W2 = (const float*)d_in[12];
  const float* b2 = (const float*)d_in[13];
  const float* gamma = (const float*)d_in[14];
  const float* beta = (const float*)d_in[15];
  float* out = (float*)d_out;

  char* ws = (char*)d_ws;
  size_t off = 0;
  auto alloc = [&](size_t bytes) {
    char* p = ws + off;
    off = (off + bytes + 255) & ~(size_t)255;
    return p;
  };
  unsigned short* embB = (unsigned short*)alloc((size_t)Mm * Dd * 2);
  unsigned short* WtQKV = (unsigned short*)alloc((size_t)1536 * 512 * 2);
  unsigned short* WtC = (unsigned short*)alloc((size_t)512 * 512 * 2);
  unsigned short* Wt1 = (unsigned short*)alloc((size_t)2048 * 512 * 2);
  unsigned short* Wt2 = (unsigned short*)alloc((size_t)512 * 2048 * 2);
  unsigned short* Qb = (unsigned short*)alloc((size_t)Mm * Dd * 2);
  unsigned short* Kb = (unsigned short*)alloc((size_t)Mm * Dd * 2);
  unsigned short* Vt = (unsigned short*)alloc((size_t)Mm * Dd * 2);
  unsigned short* Hcat = (unsigned short*)alloc((size_t)Mm * Dd * 2);
  float* resF = (float*)alloc((size_t)Mm * Dd * 4);
  unsigned short* HnB = (unsigned short*)alloc((size_t)Mm * Dd * 2);
  unsigned short* G = Qb;   // reuse: dead after proj GEMM

  prep_all<<<7200, 256, 0, stream>>>(emb, Wq, Wk, Wv, Wc, W1, W2,
                                     embB, WtQKV, WtC, Wt1, Wt2,
                                     out + (size_t)Mm * Dd);

  gemm_bt<0, 4><<<768, 256, 0, stream>>>(embB, WtQKV, bq, bk, bv, nullptr, nullptr,
                                         Qb, Kb, Vt, Mm, 1536, 512, 12);
  attn_kernel<<<512, 512, 0, stream>>>(Qb, Kb, Vt, Hcat);
  gemm_bt<1, 2><<<512, 256, 0, stream>>>(Hcat, WtC, bc, nullptr, nullptr, emb, resF,
                                         nullptr, nullptr, nullptr, Mm, 512, 512, 8);
  layernorm_k<<<2048, 256, 0, stream>>>(resF, gamma, beta, HnB);
  gemm_bt<2, 4><<<1024, 256, 0, stream>>>(HnB, Wt1, b1, nullptr, nullptr, nullptr, nullptr,
                                          G, nullptr, nullptr, Mm, 2048, 512, 16);
  gemm_bt<3, 2><<<512, 256, 0, stream>>>(G, Wt2, b2, nullptr, nullptr, nullptr, out,
                                         nullptr, nullptr, nullptr, Mm, 512, 2048, 8);
}

// Round 18
// 164.421 us; speedup vs baseline: 1.0370x; 1.0154x over previous
//
#include <hip/hip_runtime.h>
#include <hip/hip_bf16.h>
#include <cstdint>
#include <cstddef>

typedef short  s16x8 __attribute__((ext_vector_type(8)));
typedef short  s16x4 __attribute__((ext_vector_type(4)));
typedef float  f32x4 __attribute__((ext_vector_type(4)));
typedef unsigned u32x2 __attribute__((ext_vector_type(2)));

static constexpr int Bb = 4, Ss = 2048, Dd = 512, Hh = 8, HDd = 64, FFf = 2048;
static constexpr int Mm = Bb * Ss; // 8192

__device__ __forceinline__ unsigned short f2bf(float f) {
  unsigned u = __float_as_uint(f);
  u += 0x7FFFu + ((u >> 16) & 1u);   // RNE
  return (unsigned short)(u >> 16);
}

__device__ __forceinline__ float bf2f(unsigned short u) {
  return __uint_as_float((unsigned)u << 16);
}

__device__ __forceinline__ unsigned cvt_pk_bf16(float lo, float hi) {
  unsigned r;
  asm("v_cvt_pk_bf16_f32 %0, %1, %2" : "=v"(r) : "v"(lo), "v"(hi));
  return r;
}

// raw hardware exp2 (inputs bounded by defer-max; underflow->0 is desired)
__device__ __forceinline__ float exp2_raw(float x) {
  float r;
  asm("v_exp_f32 %0, %1\n\ts_nop 0" : "=v"(r) : "v"(x));
  return r;
}

#define GLOAD_LDS16(gp, lp)                                                     \
  __builtin_amdgcn_global_load_lds((const __attribute__((address_space(1))) void*)(gp), \
                                   (__attribute__((address_space(3))) void*)(lp), 16, 0, 0)

// ---------- fused prep: emb cvt + QKV weight prep + 3 transposes + mask ----------
__device__ __forceinline__ void xpose_tile(const float* __restrict__ in,
                                           unsigned short* __restrict__ out,
                                           int K, int N, int bx, int by, float (*t)[33]) {
  const int lx = threadIdx.x & 31, ly = threadIdx.x >> 5;
  const int n0 = bx * 32, k0 = by * 32;
#pragma unroll
  for (int r = 0; r < 4; ++r) t[ly + r * 8][lx] = in[(size_t)(k0 + ly + r * 8) * N + n0 + lx];
  __syncthreads();
#pragma unroll
  for (int r = 0; r < 4; ++r)
    out[(size_t)(n0 + ly + r * 8) * K + k0 + lx] = f2bf(t[lx][ly + r * 8]);
}

__global__ __launch_bounds__(256) void prep_all(
    const float* __restrict__ emb, const float* __restrict__ Wq, const float* __restrict__ Wk,
    const float* __restrict__ Wv, const float* __restrict__ Wc, const float* __restrict__ W1,
    const float* __restrict__ W2, unsigned short* __restrict__ embB,
    unsigned short* __restrict__ WtQKV, unsigned short* __restrict__ WtC,
    unsigned short* __restrict__ Wt1, unsigned short* __restrict__ Wt2,
    float* __restrict__ maskOut) {
  __shared__ float t[32][33];
  const int blk = blockIdx.x;
  if (blk < 4096) {                       // emb f32 -> bf16, 8 B/thread
    const int i = blk * 256 + threadIdx.x;
    const float4 v = reinterpret_cast<const float4*>(emb)[i];
    s16x4 o; o[0] = f2bf(v.x); o[1] = f2bf(v.y); o[2] = f2bf(v.z); o[3] = f2bf(v.w);
    reinterpret_cast<s16x4*>(embB)[i] = o;
  } else if (blk < 4864) {                // Wq/Wk/Wv [H,D,HD] -> [(sel*512+h*64+f)][d]
    const int b = blk - 4096;
    const int bx = b & 15, by = (b >> 4) & 1, z = b >> 5;
    const int sel = z >> 3, h = z & 7;
    const float* W = sel == 0 ? Wq : (sel == 1 ? Wk : Wv);
    const float* inb = W + (size_t)h * 512 * 64;
    unsigned short* outb = WtQKV + (size_t)sel * 512 * 512 + (size_t)h * 64 * 512;
    const int lx = threadIdx.x & 31, ly = threadIdx.x >> 5;
    const int d0 = bx * 32, f0 = by * 32;
#pragma unroll
    for (int r = 0; r < 4; ++r) t[ly + r * 8][lx] = inb[(size_t)(d0 + ly + r * 8) * 64 + f0 + lx];
    __syncthreads();
#pragma unroll
    for (int r = 0; r < 4; ++r)
      outb[(size_t)(f0 + ly + r * 8) * 512 + d0 + lx] = f2bf(t[lx][ly + r * 8]);
  } else if (blk < 5120) {                // Wc [512,512] -> [N][K]
    const int b = blk - 4864;
    xpose_tile(Wc, WtC, 512, 512, b & 15, b >> 4, t);
  } else if (blk < 6144) {                // W1 [512,2048] -> [2048][512]
    const int b = blk - 5120;
    xpose_tile(W1, Wt1, 512, 2048, b & 63, b >> 6, t);
  } else if (blk < 7168) {                // W2 [2048,512] -> [512][2048]
    const int b = blk - 6144;
    xpose_tile(W2, Wt2, 2048, 512, b & 15, b >> 4, t);
  } else {                                // mask = 1.0f
    const int i = (blk - 7168) * 256 + threadIdx.x;
    if (i < Bb * Ss) maskOut[i] = 1.0f;
  }
}

// ---------- GEMM: C[M,N] = A[M,K](bf16) @ Bt[N,K]^T(bf16) ----------
// 3-buffer ring LDS pipeline, counted vmcnt, T2 swizzle, setprio, T1 XCD-chunked grid.
// EPI0: QKV scatter (V directly transposed). EPI1: +bias +bf16 residual -> bf16 res.
// EPI2: +bias,ReLU -> bf16. EPI3: +bias -> f32.
template<int EPI, int NI>
__global__ __launch_bounds__(256) void gemm_bt(
    const unsigned short* __restrict__ A, const unsigned short* __restrict__ Bt,
    const float* __restrict__ bias0, const float* __restrict__ bias1, const float* __restrict__ bias2,
    const unsigned short* __restrict__ addB, float* __restrict__ outF,
    unsigned short* __restrict__ outB0, unsigned short* __restrict__ outB1,
    unsigned short* __restrict__ outB2, int M, int N, int K, int nbx) {
  constexpr int BN = NI * 32;
  __shared__ alignas(16) unsigned short As[3][128 * 32];
  __shared__ alignas(16) unsigned short Bs[3][BN * 32];
  const int tid = threadIdx.x;
  const int lane = tid & 63, wid = tid >> 6;
  const int wr = wid >> 1, wc = wid & 1;
  const int fr = lane & 15, kg = lane >> 4;

  const int lin = blockIdx.x;
  const int xcd = lin & 7, idx = lin >> 3;
  const int bx = idx % nbx, ysub = idx / nbx;
  const int m0 = (xcd * 8 + ysub) * 128, n0 = bx * BN;

  const int srow = tid >> 2;
  const int schunk = (tid & 3) ^ ((tid >> 3) & 3);   // pre-swizzled source chunk
  const unsigned short* gA = A + (size_t)(m0 + srow) * K + (schunk << 3);
  const unsigned short* gB = Bt + (size_t)(n0 + srow) * K + (schunk << 3);

  auto STAGE = [&](int kt, int buf) {
    unsigned short* lA = &As[buf][wid * 512];
    unsigned short* lB = &Bs[buf][wid * 512];
    GLOAD_LDS16(gA + kt, lA);
    GLOAD_LDS16(gA + (size_t)64 * K + kt, lA + 2048);
    GLOAD_LDS16(gB + kt, lB);
    if constexpr (NI == 4) GLOAD_LDS16(gB + (size_t)64 * K + kt, lB + 2048);
  };

  f32x4 acc[4][NI];
#pragma unroll
  for (int i = 0; i < 4; ++i)
#pragma unroll
    for (int j = 0; j < NI; ++j)
#pragma unroll
      for (int r = 0; r < 4; ++r) acc[i][j][r] = 0.f;

  STAGE(0, 0);
  STAGE(32, 1);
  const int nk = K >> 5;
  int cur = 0;
  const int rchunk = (kg ^ ((fr >> 1) & 3)) << 3;    // swizzled read chunk (shorts)
  for (int ki = 0; ki < nk; ++ki) {
    const int pre = cur == 0 ? 2 : cur - 1;
    __builtin_amdgcn_s_barrier();
    if (ki + 2 < nk) {
      STAGE((ki + 2) << 5, pre);
      if constexpr (NI == 4)
        asm volatile("s_waitcnt vmcnt(8)" ::: "memory");
      else
        asm volatile("s_waitcnt vmcnt(6)" ::: "memory");
    } else if (ki + 1 < nk) {
      if constexpr (NI == 4)
        asm volatile("s_waitcnt vmcnt(4)" ::: "memory");
      else
        asm volatile("s_waitcnt vmcnt(3)" ::: "memory");
    } else {
      asm volatile("s_waitcnt vmcnt(0)" ::: "memory");
    }
    __builtin_amdgcn_sched_barrier(0);
    __builtin_amdgcn_s_barrier();
    __builtin_amdgcn_sched_barrier(0);

    s16x8 af[4], bfv[NI];
#pragma unroll
    for (int i = 0; i < 4; ++i)
      af[i] = *reinterpret_cast<const s16x8*>(&As[cur][(wr * 64 + i * 16 + fr) * 32 + rchunk]);
#pragma unroll
    for (int i = 0; i < NI; ++i)
      bfv[i] = *reinterpret_cast<const s16x8*>(
          &Bs[cur][(wc * (NI * 16) + i * 16 + fr) * 32 + rchunk]);
    __builtin_amdgcn_s_setprio(1);
#pragma unroll
    for (int mi = 0; mi < 4; ++mi)
#pragma unroll
      for (int ni = 0; ni < NI; ++ni)
        acc[mi][ni] = __builtin_amdgcn_mfma_f32_16x16x32_bf16(af[mi], bfv[ni], acc[mi][ni], 0, 0, 0);
    __builtin_amdgcn_s_setprio(0);
    cur = cur == 2 ? 0 : cur + 1;
  }

#pragma unroll
  for (int mi = 0; mi < 4; ++mi)
#pragma unroll
    for (int ni = 0; ni < NI; ++ni) {
      if constexpr (EPI == 0) {
        const int col = n0 + wc * (NI * 16) + ni * 16 + fr;
        const int sel = col >> 9, c = col & 511;
        const int h = c >> 6, f = c & 63;
        const int row0 = m0 + wr * 64 + mi * 16 + kg * 4;
        const int b = row0 >> 11, s0 = row0 & 2047;
        if (sel == 2) {
          const float bsv = bias2[c];
          u32x2 pk;
          pk[0] = (unsigned)f2bf(acc[mi][ni][0] + bsv) |
                  ((unsigned)f2bf(acc[mi][ni][1] + bsv) << 16);
          pk[1] = (unsigned)f2bf(acc[mi][ni][2] + bsv) |
                  ((unsigned)f2bf(acc[mi][ni][3] + bsv) << 16);
          *reinterpret_cast<u32x2*>(
              &outB2[((size_t)((b << 3) + h) * 64 + f) * 2048 + s0]) = pk;
        } else {
          const float* bs = sel == 0 ? bias0 : bias1;
          unsigned short* ob = sel == 0 ? outB0 : outB1;
          const float bv = bs[c];
#pragma unroll
          for (int r = 0; r < 4; ++r)
            ob[((size_t)((b << 3) + h) * 2048 + s0 + r) * 64 + f] =
                f2bf(acc[mi][ni][r] + bv);
        }
      } else {
#pragma unroll
        for (int r = 0; r < 4; ++r) {
          const int row = m0 + wr * 64 + mi * 16 + kg * 4 + r;
          const int col = n0 + wc * (NI * 16) + ni * 16 + fr;
          float v = acc[mi][ni][r];
          if constexpr (EPI == 1) {
            const size_t idx2 = (size_t)row * 512 + col;
            outB0[idx2] = f2bf(v + bias0[col] + bf2f(addB[idx2]));
          } else if constexpr (EPI == 2) {
            v += bias0[col];
            outB0[(size_t)row * 2048 + col] = f2bf(v > 0.f ? v : 0.f);
          } else {
            outF[(size_t)row * 512 + col] = v + bias0[col];
          }
        }
      }
    }
}

// ---------- flash attention (r15 version, reverted): 8-wave blocks, K dbuf, V single,
// 3 barriers + counted vmcnt(1), cvt_pk, raw v_exp, defer-max, setprio, XCD co-location.
__global__ __launch_bounds__(512) void attn_kernel(const unsigned short* __restrict__ Q,
                                                   const unsigned short* __restrict__ Kx,
                                                   const unsigned short* __restrict__ V,
                                                   unsigned short* __restrict__ Hcat) {
  const int lane = threadIdx.x & 63, wid = threadIdx.x >> 6;   // 8 waves
  const int fr = lane & 15, kg = lane >> 4;
  const int lin = blockIdx.x;
  const int xcd = lin & 7, idx = lin >> 3;
  const int bh = xcd * 4 + (idx & 3);          // 4 heads per XCD
  const int qi = idx >> 2;                     // 0..15, 128 q-rows each
  const int b = bh >> 3, h = bh & 7;
  const int q0 = qi * 128 + wid * 16;
  const unsigned short* Qh = Q + (size_t)bh * Ss * HDd;
  const unsigned short* Kh = Kx + (size_t)bh * Ss * HDd;
  const unsigned short* Vh = V + (size_t)bh * HDd * Ss;

  __shared__ alignas(16) unsigned short Ks[2][64 * 64];  // [t-row][d-col] swizzled
  __shared__ alignas(16) unsigned short Vs[64 * 64];     // [d-row][t-col] swizzled
  __shared__ alignas(16) unsigned short P[8][16][72];    // per-wave [q][t]

  const int srow = lane >> 3;
  const int scol = ((lane & 7) ^ srow) << 3;  // shorts, inverse swizzle on source
  // each wave stages rows [8*wid, 8*wid+8) with ONE instruction per tile
  const unsigned short* gK = Kh + (size_t)(8 * wid + srow) * 64 + scol;
  const unsigned short* gV = Vh + (size_t)(8 * wid + srow) * 2048 + scol;
  unsigned short* lKa = &Ks[0][wid * 512];
  unsigned short* lKb = &Ks[1][wid * 512];
  unsigned short* lV  = &Vs[wid * 512];

  // Q as B-fragment: col=q=fr, k=kg*8+j
  s16x8 bq[2];
#pragma unroll
  for (int kb = 0; kb < 2; ++kb)
    bq[kb] = *reinterpret_cast<const s16x8*>(&Qh[(size_t)(q0 + fr) * 64 + kb * 32 + kg * 8]);

  f32x4 o[4];          // D[q = kg*4+r][d = ct*16+fr]
#pragma unroll
  for (int ct = 0; ct < 4; ++ct)
#pragma unroll
    for (int r = 0; r < 4; ++r) o[ct][r] = 0.f;
  float mr = -1e30f, lsum = 0.f;   // softmax state for q-row = fr (log2 units)

  const float iscL = 1.4426950408889634f * 0.044194173824159216f; // log2(e)/sqrt(512)
  const int swz = (fr & 7) << 3;   // read-side XOR (shorts)

  // prologue: stage K[0] then V[0]
  GLOAD_LDS16(gK, lKa);
  GLOAD_LDS16(gV, lV);

#pragma unroll 1
  for (int t = 0; t < 32; ++t) {
    const int kt = t * 64;
    const int ktn = (kt + 64) & 2047;            // wraps (dummy stage) at t=31
    const unsigned short* KsC = Ks[t & 1];
    unsigned short* nK = (t & 1) ? lKa : lKb;

    // wait my K[t] (1 oldest of [K:1, V:1]); barrier -> everyone's landed
    asm volatile("s_waitcnt vmcnt(1)" ::: "memory");
    __builtin_amdgcn_sched_barrier(0);
    __builtin_amdgcn_s_barrier();
    __builtin_amdgcn_sched_barrier(0);

    // QK^T swapped: D[t'][q], lane holds q=fr, t' = ct*16 + kg*4 + r
    f32x4 sc[4];
#pragma unroll
    for (int ct = 0; ct < 4; ++ct)
#pragma unroll
      for (int r = 0; r < 4; ++r) sc[ct][r] = 0.f;
    __builtin_amdgcn_s_setprio(1);
#pragma unroll
    for (int ct = 0; ct < 4; ++ct)
#pragma unroll
      for (int kb = 0; kb < 2; ++kb) {
        const s16x8 kf = *reinterpret_cast<const s16x8*>(
            &KsC[(ct * 16 + fr) * 64 + (((kg << 3) + (kb << 5)) ^ swz)]);
        sc[ct] = __builtin_amdgcn_mfma_f32_16x16x32_bf16(kf, bq[kb], sc[ct], 0, 0, 0);
      }
    __builtin_amdgcn_s_setprio(0);

    // issue next K tile stage (into the buffer QK(t-1) finished with)
    GLOAD_LDS16(gK + (size_t)ktn * 64, nK);

    // lane-local max over this lane's 16 scores (scaled units)
    float mxl;
    {
      const float a0 = fmaxf(fmaxf(sc[0][0], sc[0][1]), fmaxf(sc[0][2], sc[0][3]));
      const float a1 = fmaxf(fmaxf(sc[1][0], sc[1][1]), fmaxf(sc[1][2], sc[1][3]));
      const float a2 = fmaxf(fmaxf(sc[2][0], sc[2][1]), fmaxf(sc[2][2], sc[2][3]));
      const float a3 = fmaxf(fmaxf(sc[3][0], sc[3][1]), fmaxf(sc[3][2], sc[3][3]));
      mxl = fmaxf(fmaxf(a0, a1), fmaxf(a2, a3)) * iscL;
    }
    // defer-max (T13): rescale only when some lane's max grew past mr+8 (wave-uniform)
    if (!__all(mxl <= mr + 8.0f)) {
      float mx = fmaxf(mxl, __shfl_xor(mxl, 16));
      mx = fmaxf(mx, __shfl_xor(mx, 32));
      const float mn = fmaxf(mr, mx);
      const float corr = exp2_raw(mr - mn);
      mr = mn;
      lsum *= corr;
      float corrq[4];
#pragma unroll
      for (int r = 0; r < 4; ++r) corrq[r] = __shfl(corr, kg * 4 + r);
#pragma unroll
      for (int ct = 0; ct < 4; ++ct)
#pragma unroll
        for (int r = 0; r < 4; ++r) o[ct][r] *= corrq[r];
    }

    // P = exp2(sc*iscL - mr), bounded by 2^8; raw v_exp + v_cvt_pk_bf16_f32
    float ps0 = 0.f, ps1 = 0.f;
#pragma unroll
    for (int ct = 0; ct < 4; ++ct) {
      float p0 = exp2_raw(__builtin_fmaf(sc[ct][0], iscL, -mr));
      float p1 = exp2_raw(__builtin_fmaf(sc[ct][1], iscL, -mr));
      float p2 = exp2_raw(__builtin_fmaf(sc[ct][2], iscL, -mr));
      float p3 = exp2_raw(__builtin_fmaf(sc[ct][3], iscL, -mr));
      ps0 += (p0 + p1);
      ps1 += (p2 + p3);
      u32x2 pk;
      pk[0] = cvt_pk_bf16(p0, p1);
      pk[1] = cvt_pk_bf16(p2, p3);
      *reinterpret_cast<u32x2*>(&P[wid][fr][ct * 16 + kg * 4]) = pk;
    }
    lsum += ps0 + ps1;

    // wait my V[t] (outstanding [V:1, K[t+1]:1] -> vmcnt(1)); barrier -> everyone's V ready
    asm volatile("s_waitcnt vmcnt(1)" ::: "memory");
    __builtin_amdgcn_sched_barrier(0);
    __builtin_amdgcn_s_barrier();
    __builtin_amdgcn_sched_barrier(0);

    // PV: A = P rows (q=fr), B = Vs rows (d=ct*16+fr)
    const s16x8 pa0 = *reinterpret_cast<const s16x8*>(&P[wid][fr][kg * 8]);
    const s16x8 pa1 = *reinterpret_cast<const s16x8*>(&P[wid][fr][32 + kg * 8]);
    __builtin_amdgcn_s_setprio(1);
#pragma unroll
    for (int ct = 0; ct < 4; ++ct) {
      const s16x8 bv0 = *reinterpret_cast<const s16x8*>(
          &Vs[(ct * 16 + fr) * 64 + (((kg << 3) + 0) ^ swz)]);
      o[ct] = __builtin_amdgcn_mfma_f32_16x16x32_bf16(pa0, bv0, o[ct], 0, 0, 0);
      const s16x8 bv1 = *reinterpret_cast<const s16x8*>(
          &Vs[(ct * 16 + fr) * 64 + (((kg << 3) + 32) ^ swz)]);
      o[ct] = __builtin_amdgcn_mfma_f32_16x16x32_bf16(pa1, bv1, o[ct], 0, 0, 0);
    }
    __builtin_amdgcn_s_setprio(0);

    // all PV reads of Vs done -> safe to overwrite; issue V[t+1] stage
    __builtin_amdgcn_s_barrier();
    __builtin_amdgcn_sched_barrier(0);
    GLOAD_LDS16(gV + ktn, lV);
  }

  lsum += __shfl_xor(lsum, 16);
  lsum += __shfl_xor(lsum, 32);
  float invq[4];
#pragma unroll
  for (int r = 0; r < 4; ++r) invq[r] = 1.0f / __shfl(lsum, kg * 4 + r);
#pragma unroll
  for (int ct = 0; ct < 4; ++ct)
#pragma unroll
    for (int r = 0; r < 4; ++r) {
      const int qrow = q0 + kg * 4 + r;
      Hcat[(size_t)(b * Ss + qrow) * Dd + h * 64 + ct * 16 + fr] = f2bf(o[ct][r] * invq[r]);
    }
}

// ---------- LayerNorm: one wave per row of 512, bf16 input ----------
__global__ __launch_bounds__(256) void layernorm_k(const unsigned short* __restrict__ res,
                                                   const float* __restrict__ gamma,
                                                   const float* __restrict__ beta,
                                                   unsigned short* __restrict__ out) {
  const int lane = threadIdx.x & 63, wid = threadIdx.x >> 6;
  const int row = blockIdx.x * 4 + wid;
  const s16x8 v = *reinterpret_cast<const s16x8*>(res + (size_t)row * 512 + lane * 8);
  float x[8];
#pragma unroll
  for (int j = 0; j < 8; ++j) x[j] = bf2f((unsigned short)v[j]);
  float s = 0.f, q = 0.f;
#pragma unroll
  for (int j = 0; j < 8; ++j) { s += x[j]; q += x[j] * x[j]; }
#pragma unroll
  for (int off = 32; off; off >>= 1) { s += __shfl_xor(s, off); q += __shfl_xor(q, off); }
  const float mean = s * (1.f / 512.f);
  const float var = q * (1.f / 512.f) - mean * mean;
  const float rstd = rsqrtf(var + 1e-5f);
  s16x8 o;
#pragma unroll
  for (int j = 0; j < 8; ++j) {
    const int c = lane * 8 + j;
    o[j] = f2bf((x[j] - mean) * rstd * gamma[c] + beta[c]);
  }
  *reinterpret_cast<s16x8*>(out + (size_t)row * 512 + lane * 8) = o;
}

extern "C" void kernel_launch(void* const* d_in, const int* in_sizes, int n_in,
                              void* d_out, int out_size, void* d_ws, size_t ws_size,
                              hipStream_t stream) {
  const float* emb = (const float*)d_in[0];
  const float* Wq = (const float*)d_in[2];
  const float* bq = (const float*)d_in[3];
  const float* Wk = (const float*)d_in[4];
  const float* bk = (const float*)d_in[5];
  const float* Wv = (const float*)d_in[6];
  const float* bv = (const float*)d_in[7];
  const float* Wc = (const float*)d_in[8];
  const float* bc = (const float*)d_in[9];
  const float* W1 = (const float*)d_in[10];
  const float* b1 = (const float*)d_in[11];
  const float* W2 = (const float*)d_in[12];
  const float* b2 = (const float*)d_in[13];
  const float* gamma = (const float*)d_in[14];
  const float* beta = (const float*)d_in[15];
  float* out = (float*)d_out;

  char* ws = (char*)d_ws;
  size_t off = 0;
  auto alloc = [&](size_t bytes) {
    char* p = ws + off;
    off = (off + bytes + 255) & ~(size_t)255;
    return p;
  };
  unsigned short* embB = (unsigned short*)alloc((size_t)Mm * Dd * 2);
  unsigned short* WtQKV = (unsigned short*)alloc((size_t)1536 * 512 * 2);
  unsigned short* WtC = (unsigned short*)alloc((size_t)512 * 512 * 2);
  unsigned short* Wt1 = (unsigned short*)alloc((size_t)2048 * 512 * 2);
  unsigned short* Wt2 = (unsigned short*)alloc((size_t)512 * 2048 * 2);
  unsigned short* Qb = (unsigned short*)alloc((size_t)Mm * Dd * 2);
  unsigned short* Kb = (unsigned short*)alloc((size_t)Mm * Dd * 2);
  unsigned short* Vt = (unsigned short*)alloc((size_t)Mm * Dd * 2);
  unsigned short* Hcat = (unsigned short*)alloc((size_t)Mm * Dd * 2);
  unsigned short* resB = (unsigned short*)alloc((size_t)Mm * Dd * 2);
  unsigned short* HnB = (unsigned short*)alloc((size_t)Mm * Dd * 2);
  unsigned short* G = Qb;   // reuse: dead after proj GEMM

  prep_all<<<7200, 256, 0, stream>>>(emb, Wq, Wk, Wv, Wc, W1, W2,
                                     embB, WtQKV, WtC, Wt1, Wt2,
                                     out + (size_t)Mm * Dd);

  gemm_bt<0, 4><<<768, 256, 0, stream>>>(embB, WtQKV, bq, bk, bv, nullptr, nullptr,
                                         Qb, Kb, Vt, Mm, 1536, 512, 12);
  attn_kernel<<<512, 512, 0, stream>>>(Qb, Kb, Vt, Hcat);
  gemm_bt<1, 2><<<512, 256, 0, stream>>>(Hcat, WtC, bc, nullptr, nullptr, embB, nullptr,
                                         resB, nullptr, nullptr, Mm, 512, 512, 8);
  layernorm_k<<<2048, 256, 0, stream>>>(resB, gamma, beta, HnB);
  gemm_bt<2, 4><<<1024, 256, 0, stream>>>(HnB, Wt1, b1, nullptr, nullptr, nullptr, nullptr,
                                          G, nullptr, nullptr, Mm, 2048, 512, 16);
  gemm_bt<3, 2><<<512, 256, 0, stream>>>(G, Wt2, b2, nullptr, nullptr, nullptr, out,
                                         nullptr, nullptr, nullptr, Mm, 512, 2048, 8);
}